// Round 7
// baseline (232.455 us; speedup 1.0000x reference)
//
#include <hip/hip_runtime.h>
#include <stdint.h>

#define N_OPS 102400
#define NDAG 1024
#define EMB 256

typedef short v8s __attribute__((ext_vector_type(8)));
typedef float v4f __attribute__((ext_vector_type(4)));

__device__ __forceinline__ unsigned short f2bf(float f) {
  union { float f; unsigned int i; } v; v.f = f;
  unsigned int r = v.i + 0x7fffu + ((v.i >> 16) & 1u);
  return (unsigned short)(r >> 16);
}

// ---------------------------------------------------------------------------
// K1: 1856 blocks x 256. Self-contained (no cross-block dataflow):
//  blocks 0..1599  : op branch for rows [b*64, b*64+64). Per-block: scan
//                    num_ops in LDS, repack W1-x/W2 frags to LDS, compute
//                    z-bias and own-dag y-bias, then MFMA pipeline (as R5),
//                    e -> outF[0:N_OPS], partial sum -> bsum[b].
//  blocks 1600..1855: prlvl branch for dags (b-1600)*4 .. +4. Per-block
//                    z/y bias from prW1, logits, per-wave softmax -> outF.
// ---------------------------------------------------------------------------
__global__ __launch_bounds__(256) void k_main(
    const int* __restrict__ num_ops,
    const float* __restrict__ x, const float* __restrict__ y,
    const float* __restrict__ z,
    const float* __restrict__ opmsk, const float* __restrict__ prmsk,
    const float* __restrict__ opW1, const float* __restrict__ opb1,
    const float* __restrict__ opW2, const float* __restrict__ opb2,
    const float* __restrict__ opW3, const float* __restrict__ opb3,
    const float* __restrict__ prW1, const float* __restrict__ prb1,
    const float* __restrict__ prW2, const float* __restrict__ prb2,
    const float* __restrict__ prW3, const float* __restrict__ prb3,
    float* __restrict__ bsum, float* __restrict__ outF)
{
  __shared__ int st[1025];
  __shared__ int sc[256];
  __shared__ float sums[8][32];
  __shared__ float biasL[17][32];     // op: y-bias per local dag; prlvl: 4 dags
  __shared__ float zL[32];            // z-bias (+b1 folded)
  __shared__ float limW[32];          // prlvl: W1 limit row
  __shared__ __align__(16) unsigned short wbL[8192];
  __shared__ __align__(16) unsigned short wb2L[512];
  __shared__ __align__(16) unsigned short h1lds[4][16][40];
  __shared__ float red[4];

  int t = threadIdx.x, b = blockIdx.x;
  int j = t & 31, p = t >> 5;

  if (b < 1600) {
    // ---------- phase a: block-local setup ----------
    {
      int i0 = t * 4;
      int v0 = num_ops[i0], v1 = num_ops[i0 + 1];
      int v2 = num_ops[i0 + 2], v3 = num_ops[i0 + 3];
      int s = v0 + v1 + v2 + v3;
      sc[t] = s;
      __syncthreads();
      for (int off = 1; off < 256; off <<= 1) {
        int tmp = (t >= off) ? sc[t - off] : 0;
        __syncthreads();
        sc[t] += tmp;
        __syncthreads();
      }
      int excl = sc[t] - s;
      st[i0]     = excl;
      st[i0 + 1] = excl + v0;
      st[i0 + 2] = excl + v0 + v1;
      st[i0 + 3] = excl + v0 + v1 + v2;
      if (t == 255) st[1024] = sc[255];
    }
    // W1 x-part -> bf16 MFMA B frags in LDS (same mapping as R5 PASS):
    // e = ((ks*2+f)*64 + lane)*8 + j3 ; B[k=ks*32+(lane>>4)*8+j3][n=(lane&15)+16f]
    for (int e = t; e < 8192; e += 256) {
      int j3 = e & 7, l = (e >> 3) & 63, f = (e >> 9) & 1, ks = e >> 10;
      int k = ks * 32 + ((l >> 4) << 3) + j3;
      int col = (l & 15) | (f << 4);
      wbL[e] = f2bf(opW1[k * 32 + col]);
    }
    // W2 (32x16) B frag in LDS: e = lane*8 + j3
    for (int e = t; e < 512; e += 256) {
      int j3 = e & 7, l = e >> 3;
      int k = ((l >> 4) << 3) + j3, n = l & 15;
      wb2L[e] = f2bf(opW2[k * 16 + n]);
    }
    // z-bias (+b1)
    {
      float a = 0;
      for (int k = p * 32; k < p * 32 + 32; ++k) a += z[k] * opW1[(512 + k) * 32 + j];
      sums[p][j] = a;
    }
    __syncthreads();
    if (t < 32) {
      float s2 = 0;
      for (int q2 = 0; q2 < 8; ++q2) s2 += sums[q2][t];
      zL[t] = s2 + opb1[t];
    }
    __syncthreads();
    // dag span of this block's 64 rows, then per-dag y-bias
    int rowBase = b * 64;
    int lo = 0, hi = 1024;
    while (hi - lo > 1) { int mid = (lo + hi) >> 1; if (st[mid] <= rowBase) lo = mid; else hi = mid; }
    int dagF = lo;
    lo = dagF; hi = 1024;
    while (hi - lo > 1) { int mid = (lo + hi) >> 1; if (st[mid] <= rowBase + 63) lo = mid; else hi = mid; }
    int nd = lo - dagF + 1;
    if (nd > 17) nd = 17;   // 64 rows span <=2 dags for this input (100 ops/dag)
    for (int dl = 0; dl < nd; ++dl) {
      int dag = dagF + dl;
      const float* yr = y + (size_t)dag * EMB;
      float a = 0;
      for (int k = p * 32; k < p * 32 + 32; ++k) a += yr[k] * opW1[(256 + k) * 32 + j];
      sums[p][j] = a;
      __syncthreads();
      if (t < 32) {
        float s2 = 0;
        for (int q2 = 0; q2 < 8; ++q2) s2 += sums[q2][t];
        biasL[dl][t] = s2;
      }
      __syncthreads();
    }

    // ---------- phase b: MFMA pipeline (identical math to R5 PASS) ----------
    int wave = t >> 6, l = t & 63;
    int m = l & 15, q = l >> 4;
    int rowB = rowBase + wave * 16;
    const v8s* bmat = (const v8s*)wbL;
    v4f acc0 = {0, 0, 0, 0}, acc1 = {0, 0, 0, 0};
    const float* xrow = x + (size_t)(rowB + m) * EMB + q * 8;
#pragma unroll
    for (int ks = 0; ks < 8; ++ks) {
      float4 xa = *(const float4*)(xrow + ks * 32);
      float4 xb = *(const float4*)(xrow + ks * 32 + 4);
      v8s a;
      a[0] = (short)f2bf(xa.x); a[1] = (short)f2bf(xa.y);
      a[2] = (short)f2bf(xa.z); a[3] = (short)f2bf(xa.w);
      a[4] = (short)f2bf(xb.x); a[5] = (short)f2bf(xb.y);
      a[6] = (short)f2bf(xb.z); a[7] = (short)f2bf(xb.w);
      v8s b0 = bmat[(ks * 2 + 0) * 64 + l];
      v8s b1 = bmat[(ks * 2 + 1) * 64 + l];
      acc0 = __builtin_amdgcn_mfma_f32_16x16x32_bf16(a, b0, acc0, 0, 0, 0);
      acc1 = __builtin_amdgcn_mfma_f32_16x16x32_bf16(a, b1, acc1, 0, 0, 0);
    }
    int rr0 = rowB + q * 4;
    int dag = dagF;
    while (dag < 1023 && st[dag + 1] <= rr0) ++dag;
    float z0 = zL[m], z1 = zL[m + 16];
#pragma unroll
    for (int r = 0; r < 4; ++r) {
      int rr = rr0 + r;
      while (dag < 1023 && st[dag + 1] <= rr) ++dag;
      int di = dag - dagF; if (di > 16) di = 16;
      float v0 = acc0[r] + biasL[di][m] + z0;
      float v1 = acc1[r] + biasL[di][m + 16] + z1;
      v0 = fmaxf(v0, 0.0f); v1 = fmaxf(v1, 0.0f);
      h1lds[wave][q * 4 + r][m]      = f2bf(v0);
      h1lds[wave][q * 4 + r][m + 16] = f2bf(v1);
    }
    __asm__ volatile("s_waitcnt lgkmcnt(0)" ::: "memory");
    v8s a2 = *(const v8s*)(&h1lds[wave][m][q * 8]);   // A2[m][q*8+j]
    v8s b2frag = ((const v8s*)wb2L)[l];
    v4f zero4 = {0, 0, 0, 0};
    v4f c2 = __builtin_amdgcn_mfma_f32_16x16x32_bf16(a2, b2frag, zero4, 0, 0, 0);

    float b2f = opb2[m];
    float w3f = opW3[m];
    float b3f = opb3[0];
    float sloc = 0.0f;
#pragma unroll
    for (int r = 0; r < 4; ++r) {
      float h2 = fmaxf(c2[r] + b2f, 0.0f);
      float tv = h2 * w3f;
      tv += __shfl_xor(tv, 1, 64);
      tv += __shfl_xor(tv, 2, 64);
      tv += __shfl_xor(tv, 4, 64);
      tv += __shfl_xor(tv, 8, 64);
      if (m == 0) {
        int row = rr0 + r;
        float logit = tv + b3f - 1000.0f * (1.0f - opmsk[row]);
        float e = __expf(logit);
        outF[row] = e;                 // un-normalized e (fp32) into d_out
        sloc += e;
      }
    }
#pragma unroll
    for (int off = 1; off < 64; off <<= 1) sloc += __shfl_xor(sloc, off, 64);
    if (l == 0) red[wave] = sloc;
    __syncthreads();
    if (t == 0) bsum[b] = red[0] + red[1] + red[2] + red[3];

  } else {
    // ---------- prlvl branch: 4 dags per block ----------
    int d0 = (b - 1600) * 4;
    {
      float a = 0;
      for (int k = p * 32; k < p * 32 + 32; ++k) a += z[k] * prW1[(257 + k) * 32 + j];
      sums[p][j] = a;
    }
    __syncthreads();
    if (t < 32) {
      float s2 = 0;
      for (int q2 = 0; q2 < 8; ++q2) s2 += sums[q2][t];
      zL[t] = s2 + prb1[t];
    }
    if (t >= 32 && t < 64) limW[t - 32] = prW1[t - 32];  // W1 limit row
    __syncthreads();
    for (int dl = 0; dl < 4; ++dl) {
      const float* yr = y + (size_t)(d0 + dl) * EMB;
      float a = 0;
      for (int k = p * 32; k < p * 32 + 32; ++k) a += yr[k] * prW1[(1 + k) * 32 + j];
      sums[p][j] = a;
      __syncthreads();
      if (t < 32) {
        float s2 = 0;
        for (int q2 = 0; q2 < 8; ++q2) s2 += sums[q2][t];
        biasL[dl][t] = s2;
      }
      __syncthreads();
    }
    int wave = t >> 6, w = t & 63;
    int d = d0 + wave;
    float h1[32];
    float limit = (float)(w + 1);
#pragma unroll
    for (int j2 = 0; j2 < 32; ++j2)
      h1[j2] = fmaxf(biasL[wave][j2] + zL[j2] + limit * limW[j2], 0.0f);
    float logit = prb3[0];
#pragma unroll
    for (int n = 0; n < 16; ++n) {
      float acc = prb2[n];
#pragma unroll
      for (int j2 = 0; j2 < 32; ++j2) acc += h1[j2] * prW2[j2 * 16 + n];
      logit += fmaxf(acc, 0.0f) * prW3[n];
    }
    logit -= 1000.0f * (1.0f - prmsk[d * 64 + w]);
    float mx = logit;
#pragma unroll
    for (int off = 1; off < 64; off <<= 1) mx = fmaxf(mx, __shfl_xor(mx, off, 64));
    float e = __expf(logit - mx);
    float s = e;
#pragma unroll
    for (int off = 1; off < 64; off <<= 1) s += __shfl_xor(s, off, 64);
    outF[N_OPS + d * 64 + w] = e / s;
  }
}

// ---------------------------------------------------------------------------
// K2: 100 blocks. Each block redundantly reduces bsum[1600] -> 1/S, then
// normalizes its 1024 e-values in d_out (float4).
// ---------------------------------------------------------------------------
__global__ __launch_bounds__(256) void k_norm(const float* __restrict__ bsum,
                                              float* __restrict__ outF)
{
  __shared__ float wsum[4];
  int t = threadIdx.x, b = blockIdx.x;
  int wave = t >> 6, lane = t & 63;
  float s = 0.0f;
  for (int i = t; i < 1600; i += 256) s += bsum[i];
#pragma unroll
  for (int off = 1; off < 64; off <<= 1) s += __shfl_xor(s, off, 64);
  if (lane == 0) wsum[wave] = s;
  __syncthreads();
  float inv = 1.0f / (wsum[0] + wsum[1] + wsum[2] + wsum[3]);
  int i = b * 1024 + t * 4;
  float4 ev = *(const float4*)(outF + i);
  ev.x *= inv; ev.y *= inv; ev.z *= inv; ev.w *= inv;
  *((float4*)(outF + i)) = ev;
}

extern "C" void kernel_launch(void* const* d_in, const int* in_sizes, int n_in,
                              void* d_out, int out_size, void* d_ws, size_t ws_size,
                              hipStream_t stream) {
  const int* num_ops = (const int*)d_in[0];
  const float* x     = (const float*)d_in[3];
  const float* y     = (const float*)d_in[4];
  const float* z     = (const float*)d_in[5];
  const float* opmsk = (const float*)d_in[6];
  const float* prmsk = (const float*)d_in[7];
  const float* opW1 = (const float*)d_in[8];
  const float* opb1 = (const float*)d_in[9];
  const float* opW2 = (const float*)d_in[10];
  const float* opb2 = (const float*)d_in[11];
  const float* opW3 = (const float*)d_in[12];
  const float* opb3 = (const float*)d_in[13];
  const float* prW1 = (const float*)d_in[14];
  const float* prb1 = (const float*)d_in[15];
  const float* prW2 = (const float*)d_in[16];
  const float* prb2 = (const float*)d_in[17];
  const float* prW3 = (const float*)d_in[18];
  const float* prb3 = (const float*)d_in[19];

  float* bsum = (float*)d_ws;          // 1600 f32
  float* outF = (float*)d_out;         // 167936 f32

  hipLaunchKernelGGL(k_main, dim3(1856), dim3(256), 0, stream,
      num_ops, x, y, z, opmsk, prmsk,
      opW1, opb1, opW2, opb2, opW3, opb3,
      prW1, prb1, prW2, prb2, prW3, prb3,
      bsum, outF);
  hipLaunchKernelGGL(k_norm, dim3(100), dim3(256), 0, stream, bsum, outF);
}

// Round 9
// 228.290 us; speedup vs baseline: 1.0182x; 1.0182x over previous
//
#include <hip/hip_runtime.h>
#include <stdint.h>

#define N_OPS 102400
#define NDAG 1024
#define EMB 256

typedef short v8s __attribute__((ext_vector_type(8)));
typedef float v4f __attribute__((ext_vector_type(4)));

__device__ __forceinline__ unsigned short f2bf(float f) {
  union { float f; unsigned int i; } v; v.f = f;
  unsigned int r = v.i + 0x7fffu + ((v.i >> 16) & 1u);
  return (unsigned short)(r >> 16);
}

// ---------------------------------------------------------------------------
// K1: setup. blocks 0..1023: per-dag y@W1 bias (1 dag/block).
//     block 1024: prefix scan of num_ops -> starts[0..1024].
//     block 1025: z@W1 bias (+b1 folded), MFMA B-fragment repacks.
// ---------------------------------------------------------------------------
__global__ __launch_bounds__(256) void k_setup(
    const int* __restrict__ num_ops,
    const float* __restrict__ y, const float* __restrict__ z,
    const float* __restrict__ opW1, const float* __restrict__ opb1,
    const float* __restrict__ opW2,
    const float* __restrict__ prW1, const float* __restrict__ prb1,
    float* __restrict__ ybop, float* __restrict__ ybpr,
    float* __restrict__ zop, float* __restrict__ zpr,
    int* __restrict__ starts,
    unsigned short* __restrict__ wb, unsigned short* __restrict__ wb2)
{
  int t = threadIdx.x;
  int b = blockIdx.x;
  if (b < 1024) {
    __shared__ float ylds[256];
    __shared__ float sop[8][32], spr[8][32];
    ylds[t] = y[b * EMB + t];
    __syncthreads();
    int j = t & 31, p = t >> 5;
    float ao = 0, ap = 0;
    for (int k = p * 32; k < p * 32 + 32; ++k) {
      float yk = ylds[k];
      ao += yk * opW1[(256 + k) * 32 + j];   // y-rows of op_W1
      ap += yk * prW1[(1 + k) * 32 + j];     // y-rows of pr_W1
    }
    sop[p][j] = ao; spr[p][j] = ap;
    __syncthreads();
    if (t < 64) {
      int j2 = t & 31, br = t >> 5;
      float s = 0;
      if (br == 0) {
        for (int p2 = 0; p2 < 8; ++p2) s += sop[p2][j2];
        ybop[b * 32 + j2] = s;
      } else {
        for (int p2 = 0; p2 < 8; ++p2) s += spr[p2][j2];
        ybpr[b * 32 + j2] = s;
      }
    }
  } else if (b == 1024) {
    __shared__ int sc[256];
    int i0 = t * 4;
    int v0 = num_ops[i0], v1 = num_ops[i0 + 1], v2 = num_ops[i0 + 2], v3 = num_ops[i0 + 3];
    int s = v0 + v1 + v2 + v3;
    sc[t] = s;
    __syncthreads();
    for (int off = 1; off < 256; off <<= 1) {
      int tmp = (t >= off) ? sc[t - off] : 0;
      __syncthreads();
      sc[t] += tmp;
      __syncthreads();
    }
    int excl = sc[t] - s;
    starts[i0]     = excl;
    starts[i0 + 1] = excl + v0;
    starts[i0 + 2] = excl + v0 + v1;
    starts[i0 + 3] = excl + v0 + v1 + v2;
    if (t == 255) starts[1024] = sc[255];
  } else {
    __shared__ float zs[2][8][32];
    int j = t & 31, p = t >> 5;
    float aO = 0, aP = 0;
    for (int k = p * 32; k < p * 32 + 32; ++k) {
      float zk = z[k];
      aO += zk * opW1[(512 + k) * 32 + j];   // z-rows of op_W1
      aP += zk * prW1[(257 + k) * 32 + j];   // z-rows of pr_W1
    }
    zs[0][p][j] = aO; zs[1][p][j] = aP;
    __syncthreads();
    if (t < 64) {
      int j2 = t & 31, br = t >> 5;
      float s = 0;
      for (int p2 = 0; p2 < 8; ++p2) s += zs[br][p2][j2];
      if (br == 0) zop[j2] = s + opb1[j2];   // fold b1 here
      else         zpr[j2] = s + prb1[j2];
    }
    // repack op_W1[0:256] (fp32) into per-lane contiguous bf16 MFMA B frags:
    // e = ((ks*2+f)*64 + lane)*8 + j ;  B[k=ks*32+quad*8+j][n=(lane&15)+16f]
    for (int e = t; e < 8192; e += 256) {
      int j3 = e & 7, l = (e >> 3) & 63, f = (e >> 9) & 1, ks = e >> 10;
      int k = ks * 32 + ((l >> 4) << 3) + j3;
      int col = (l & 15) | (f << 4);
      wb[e] = f2bf(opW1[k * 32 + col]);
    }
    // op_W2 (32x16) B fragment: e = lane*8 + j
    for (int e = t; e < 512; e += 256) {
      int j3 = e & 7, l = e >> 3;
      int k = ((l >> 4) << 3) + j3, n = l & 15;
      wb2[e] = f2bf(opW2[k * 16 + n]);
    }
  }
}

// ---------------------------------------------------------------------------
// K2: op branch. 1 wave = 16 rows, 4 waves/block, 1600 blocks.
//     starts staged to LDS once (1 barrier). fp32 x -> bf16 -> MFMA layer1,
//     bias+relu, LDS transpose, MFMA layer2, shuffle layer3, mask, exp.
//     e (fp32, unnormalized) -> outF[0:N_OPS]; block partial -> bsum[blk].
// ---------------------------------------------------------------------------
__global__ __launch_bounds__(256) void k_ops(
    const float* __restrict__ x, const float* __restrict__ opmsk,
    const float* __restrict__ opb2, const float* __restrict__ opW3,
    const float* __restrict__ opb3,
    const float* __restrict__ ybop, const float* __restrict__ zop,
    const int* __restrict__ starts,
    const unsigned short* __restrict__ wb, const unsigned short* __restrict__ wb2,
    float* __restrict__ outF, float* __restrict__ bsum)
{
  __shared__ int st[1025];
  __shared__ __align__(16) unsigned short h1lds[4][16][40];
  __shared__ float red[4];
  int t = threadIdx.x;
  for (int i = t; i < 1025; i += 256) st[i] = starts[i];
  __syncthreads();

  int wave = t >> 6;
  int l = t & 63;
  int m = l & 15, q = l >> 4;
  int rowBase = (blockIdx.x * 4 + wave) * 16;

  const v8s* bmat = (const v8s*)wb;
  v4f acc0 = {0, 0, 0, 0}, acc1 = {0, 0, 0, 0};
  const float* xrow = x + (size_t)(rowBase + m) * EMB + q * 8;
#pragma unroll
  for (int ks = 0; ks < 8; ++ks) {
    float4 xa = *(const float4*)(xrow + ks * 32);
    float4 xb = *(const float4*)(xrow + ks * 32 + 4);
    v8s a;
    a[0] = (short)f2bf(xa.x); a[1] = (short)f2bf(xa.y);
    a[2] = (short)f2bf(xa.z); a[3] = (short)f2bf(xa.w);
    a[4] = (short)f2bf(xb.x); a[5] = (short)f2bf(xb.y);
    a[6] = (short)f2bf(xb.z); a[7] = (short)f2bf(xb.w);
    v8s b0 = bmat[(ks * 2 + 0) * 64 + l];
    v8s b1 = bmat[(ks * 2 + 1) * 64 + l];
    acc0 = __builtin_amdgcn_mfma_f32_16x16x32_bf16(a, b0, acc0, 0, 0, 0);
    acc1 = __builtin_amdgcn_mfma_f32_16x16x32_bf16(a, b1, acc1, 0, 0, 0);
  }
  int rr0 = rowBase + q * 4;
  int lo = 0, hi = 1024;
  while (hi - lo > 1) { int mid = (lo + hi) >> 1; if (st[mid] <= rr0) lo = mid; else hi = mid; }
  int dag = lo;
  float z0 = zop[m], z1 = zop[m + 16];
#pragma unroll
  for (int r = 0; r < 4; ++r) {
    int rr = rr0 + r;
    while (dag < 1023 && st[dag + 1] <= rr) ++dag;
    float v0 = acc0[r] + ybop[dag * 32 + m] + z0;
    float v1 = acc1[r] + ybop[dag * 32 + m + 16] + z1;
    v0 = fmaxf(v0, 0.0f); v1 = fmaxf(v1, 0.0f);
    h1lds[wave][q * 4 + r][m]      = f2bf(v0);
    h1lds[wave][q * 4 + r][m + 16] = f2bf(v1);
  }
  __asm__ volatile("s_waitcnt lgkmcnt(0)" ::: "memory");
  v8s a2 = *(const v8s*)(&h1lds[wave][m][q * 8]);   // A2[m][q*8+j]
  v8s b2frag = ((const v8s*)wb2)[l];
  v4f zero4 = {0, 0, 0, 0};
  v4f c2 = __builtin_amdgcn_mfma_f32_16x16x32_bf16(a2, b2frag, zero4, 0, 0, 0);

  float b2f = opb2[m];
  float w3f = opW3[m];
  float b3f = opb3[0];
  float sloc = 0.0f;
#pragma unroll
  for (int r = 0; r < 4; ++r) {
    float h2 = fmaxf(c2[r] + b2f, 0.0f);
    float tv = h2 * w3f;                 // layer-3 partial: col m's term
    tv += __shfl_xor(tv, 1, 64);
    tv += __shfl_xor(tv, 2, 64);
    tv += __shfl_xor(tv, 4, 64);
    tv += __shfl_xor(tv, 8, 64);
    if (m == 0) {
      int row = rr0 + r;
      float logit = tv + b3f - 1000.0f * (1.0f - opmsk[row]);
      float e = __expf(logit);
      outF[row] = e;                     // un-normalized e, fp32, in d_out
      sloc += e;
    }
  }
#pragma unroll
  for (int off = 1; off < 64; off <<= 1) sloc += __shfl_xor(sloc, off, 64);
  if (l == 0) red[wave] = sloc;
  __syncthreads();
  if (t == 0) bsum[blockIdx.x] = red[0] + red[1] + red[2] + red[3];
}

// ---------------------------------------------------------------------------
// K3: blocks 0..99: reduce bsum[1600] redundantly, normalize e in-place in
//     d_out (fp32, float4). blocks 100..355: prlvl branch, 1 wave = 1 dag,
//     W2/W3/b2/z/limit-row staged in LDS (FIXED: strided + sub-range loads
//     within 256 threads), per-wave softmax over 64 workers.
// ---------------------------------------------------------------------------
__global__ __launch_bounds__(256) void k_final(
    const float* __restrict__ bsum,
    const float* __restrict__ ybpr, const float* __restrict__ zpr,
    const float* __restrict__ prW1, const float* __restrict__ prW2,
    const float* __restrict__ prb2, const float* __restrict__ prW3,
    const float* __restrict__ prb3, const float* __restrict__ prmsk,
    float* __restrict__ outF)
{
  int t = threadIdx.x;
  int b = blockIdx.x;
  if (b < 100) {
    __shared__ float wsum[4];
    int wave = t >> 6, lane = t & 63;
    float s = 0.0f;
    for (int j = t; j < 1600; j += 256) s += bsum[j];
#pragma unroll
    for (int off = 1; off < 64; off <<= 1) s += __shfl_xor(s, off, 64);
    if (lane == 0) wsum[wave] = s;
    __syncthreads();
    float inv = 1.0f / (wsum[0] + wsum[1] + wsum[2] + wsum[3]);
    int i = b * 1024 + t * 4;
    float4 ev = *(const float4*)(outF + i);
    ev.x *= inv; ev.y *= inv; ev.z *= inv; ev.w *= inv;
    *((float4*)(outF + i)) = ev;
  } else {
    __shared__ float W2l[512];
    __shared__ float W3l[16], b2l[16];
    __shared__ float zl[32], lw[32];
    for (int i = t; i < 512; i += 256) W2l[i] = prW2[i];
    if (t < 16) { W3l[t] = prW3[t]; b2l[t] = prb2[t]; }
    if (t >= 32 && t < 64)  zl[t - 32] = zpr[t - 32];
    if (t >= 64 && t < 96)  lw[t - 64] = prW1[t - 64];   // W1 limit row (row 0)
    __syncthreads();

    int wave = t >> 6, w = t & 63;
    int d = (b - 100) * 4 + wave;
    float h1[32];
    float limit = (float)(w + 1);
#pragma unroll
    for (int j = 0; j < 32; ++j) {
      float base = ybpr[d * 32 + j] + zl[j];        // zl includes pr_b1
      h1[j] = fmaxf(base + limit * lw[j], 0.0f);
    }
    float logit = prb3[0];
#pragma unroll
    for (int n = 0; n < 16; ++n) {
      float acc = b2l[n];
#pragma unroll
      for (int j = 0; j < 32; ++j) acc += h1[j] * W2l[j * 16 + n];
      logit += fmaxf(acc, 0.0f) * W3l[n];
    }
    logit -= 1000.0f * (1.0f - prmsk[d * 64 + w]);
    float mx = logit;
#pragma unroll
    for (int off = 1; off < 64; off <<= 1) mx = fmaxf(mx, __shfl_xor(mx, off, 64));
    float e = __expf(logit - mx);
    float s = e;
#pragma unroll
    for (int off = 1; off < 64; off <<= 1) s += __shfl_xor(s, off, 64);
    outF[N_OPS + d * 64 + w] = e / s;
  }
}

extern "C" void kernel_launch(void* const* d_in, const int* in_sizes, int n_in,
                              void* d_out, int out_size, void* d_ws, size_t ws_size,
                              hipStream_t stream) {
  const int* num_ops = (const int*)d_in[0];
  const float* x     = (const float*)d_in[3];
  const float* y     = (const float*)d_in[4];
  const float* z     = (const float*)d_in[5];
  const float* opmsk = (const float*)d_in[6];
  const float* prmsk = (const float*)d_in[7];
  const float* opW1 = (const float*)d_in[8];
  const float* opb1 = (const float*)d_in[9];
  const float* opW2 = (const float*)d_in[10];
  const float* opb2 = (const float*)d_in[11];
  const float* opW3 = (const float*)d_in[12];
  const float* opb3 = (const float*)d_in[13];
  const float* prW1 = (const float*)d_in[14];
  const float* prb1 = (const float*)d_in[15];
  const float* prW2 = (const float*)d_in[16];
  const float* prb2 = (const float*)d_in[17];
  const float* prW3 = (const float*)d_in[18];
  const float* prb3 = (const float*)d_in[19];

  // workspace layout (~291 KB)
  char* ws = (char*)d_ws;
  float* ybop  = (float*)(ws + 0);          // 1024*32 f32  (131072 B)
  float* ybpr  = (float*)(ws + 131072);     // 1024*32 f32  (131072 B)
  float* zop   = (float*)(ws + 262144);     // 32 f32
  float* zpr   = (float*)(ws + 262272);     // 32 f32
  int*   starts= (int*)  (ws + 262400);     // 1025 i32 (pad to 4608 B)
  unsigned short* wb  = (unsigned short*)(ws + 267008);  // 8192 bf16 (16384 B)
  unsigned short* wb2 = (unsigned short*)(ws + 283392);  // 512 bf16  (1024 B)
  float* bsum  = (float*)(ws + 284416);     // 1600 f32  (6400 B)
  float* outF  = (float*)d_out;             // 167936 f32

  hipLaunchKernelGGL(k_setup, dim3(1026), dim3(256), 0, stream,
      num_ops, y, z, opW1, opb1, opW2, prW1, prb1,
      ybop, ybpr, zop, zpr, starts, wb, wb2);
  hipLaunchKernelGGL(k_ops, dim3(1600), dim3(256), 0, stream,
      x, opmsk, opb2, opW3, opb3, ybop, zop, starts, wb, wb2, outF, bsum);
  hipLaunchKernelGGL(k_final, dim3(356), dim3(256), 0, stream,
      bsum, ybpr, zpr, prW1, prW2, prb2, prW3, prb3, prmsk, outF);
}